// Round 1
// baseline (9220.194 us; speedup 1.0000x reference)
//
#include <hip/hip_runtime.h>

#define TT 11
#define NE 100000
#define NTX 100000
#define DD 128
#define EE 500000
#define FF 394

// ---------- helpers ----------

__device__ __forceinline__ unsigned f2mono(float f) {
  unsigned u = __float_as_uint(f);
  return (u & 0x80000000u) ? ~u : (u | 0x80000000u);
}
__device__ __forceinline__ float mono2f(unsigned u) {
  return __uint_as_float((u & 0x80000000u) ? (u & 0x7fffffffu) : ~u);
}
__device__ __forceinline__ float leaky(float x) { return x >= 0.f ? x : 0.2f * x; }

// block of exactly 128 threads (2 waves); returns full sum to all threads
__device__ __forceinline__ float blockReduceSum128(float v, float* s2) {
  #pragma unroll
  for (int off = 32; off; off >>= 1) v += __shfl_down(v, off);
  if ((threadIdx.x & 63) == 0) s2[threadIdx.x >> 6] = v;
  __syncthreads();
  float r = s2[0] + s2[1];
  __syncthreads();
  return r;
}

// ---------- kernels ----------

// acc1[n,:] = b1 + tx_x[n,:] @ w1[0:FF,:]   (8 rows per block)
__global__ __launch_bounds__(128) void k_init_acc1(
    const float* __restrict__ tx, const float* __restrict__ w1,
    const float* __restrict__ b1, float* __restrict__ acc1) {
  __shared__ float sx[8][FF];
  int base = blockIdx.x * 8;
  int c = threadIdx.x;
  for (int r = 0; r < 8; ++r)
    for (int k = c; k < FF; k += DD) sx[r][k] = tx[(size_t)(base + r) * FF + k];
  __syncthreads();
  float acc[8];
  float bv = b1[c];
  #pragma unroll
  for (int r = 0; r < 8; ++r) acc[r] = bv;
  for (int k = 0; k < FF; ++k) {
    float w = w1[(size_t)k * DD + c];
    #pragma unroll
    for (int r = 0; r < 8; ++r) acc[r] = fmaf(sx[r][k], w, acc[r]);
  }
  #pragma unroll
  for (int r = 0; r < 8; ++r) acc1[(size_t)(base + r) * DD + c] = acc[r];
}

// las = lin_w @ att_src, lad = lin_w @ att_dst  (single block)
__global__ __launch_bounds__(128) void k_linw_att(
    const float* __restrict__ lin_w, const float* __restrict__ att_src,
    const float* __restrict__ att_dst, float* __restrict__ las, float* __restrict__ lad) {
  int k = threadIdx.x;
  float s = 0.f, d = 0.f;
  for (int j = 0; j < DD; ++j) {
    float w = lin_w[k * DD + j];
    s = fmaf(w, att_src[j], s);
    d = fmaf(w, att_dst[j], d);
  }
  las[k] = s;
  lad[k] = d;
}

// per node: a_s, a_d, self-loop logit, init segment max with self-loop
__global__ __launch_bounds__(128) void k_att(
    const float* __restrict__ emb_t, const int* __restrict__ idx_t,
    const float* __restrict__ las, const float* __restrict__ lad,
    float* __restrict__ a_s, float* __restrict__ a_d,
    float* __restrict__ self_e, unsigned* __restrict__ m_mono) {
  __shared__ float s2[2];
  int n = blockIdx.x, c = threadIdx.x;
  float x = emb_t[(size_t)idx_t[n] * DD + c];
  float vs = blockReduceSum128(x * las[c], s2);
  float vd = blockReduceSum128(x * lad[c], s2);
  if (c == 0) {
    a_s[n] = vs;
    a_d[n] = vd;
    float e = leaky(vs + vd);
    self_e[n] = e;
    m_mono[n] = f2mono(e);
  }
}

// xw = gather(emb_t, idx_t) @ lin_w   (8 rows per block)
__global__ __launch_bounds__(128) void k_gather_gemm(
    const float* __restrict__ emb_t, const int* __restrict__ idx_t,
    const float* __restrict__ lin_w, float* __restrict__ xw) {
  __shared__ float sx[8][DD];
  int base = blockIdx.x * 8;
  int c = threadIdx.x;
  for (int r = 0; r < 8; ++r)
    sx[r][c] = emb_t[(size_t)idx_t[base + r] * DD + c];
  __syncthreads();
  float acc[8] = {0.f, 0.f, 0.f, 0.f, 0.f, 0.f, 0.f, 0.f};
  for (int k = 0; k < DD; ++k) {
    float w = lin_w[k * DD + c];
    #pragma unroll
    for (int r = 0; r < 8; ++r) acc[r] = fmaf(sx[r][k], w, acc[r]);
  }
  #pragma unroll
  for (int r = 0; r < 8; ++r) xw[(size_t)(base + r) * DD + c] = acc[r];
}

__global__ void k_edge_max(const int* __restrict__ src, const int* __restrict__ dst,
                           const float* __restrict__ a_s, const float* __restrict__ a_d,
                           unsigned* __restrict__ m_mono) {
  int i = blockIdx.x * blockDim.x + threadIdx.x;
  if (i >= EE) return;
  int s = src[i], d = dst[i];
  float e = leaky(a_s[s] + a_d[d]);
  atomicMax(&m_mono[d], f2mono(e));
}

// decode max, init denom with self-loop term
__global__ void k_node_m(const unsigned* __restrict__ m_mono, const float* __restrict__ self_e,
                         float* __restrict__ m, float* __restrict__ denom) {
  int n = blockIdx.x * blockDim.x + threadIdx.x;
  if (n >= NE) return;
  float mv = mono2f(m_mono[n]);
  m[n] = mv;
  denom[n] = expf(self_e[n] - mv);
}

__global__ void k_edge_expsum(const int* __restrict__ src, const int* __restrict__ dst,
                              const float* __restrict__ a_s, const float* __restrict__ a_d,
                              const float* __restrict__ m, float* __restrict__ denom) {
  int i = blockIdx.x * blockDim.x + threadIdx.x;
  if (i >= EE) return;
  int s = src[i], d = dst[i];
  float e = leaky(a_s[s] + a_d[d]);
  atomicAdd(&denom[d], expf(e - m[d]));
}

// outb[n,:] = alpha_self(n) * xw[n,:]
__global__ void k_self_out(const float* __restrict__ xw, const float* __restrict__ self_e,
                           const float* __restrict__ m, const float* __restrict__ denom,
                           float* __restrict__ outb) {
  int i = blockIdx.x * blockDim.x + threadIdx.x;
  if (i >= NE * DD) return;
  int n = i >> 7;
  float alpha = expf(self_e[n] - m[n]) / (denom[n] + 1e-16f);
  outb[i] = alpha * xw[i];
}

// one block (128 lanes) per edge: outb[d,:] += alpha_e * xw[s,:]
__global__ __launch_bounds__(128) void k_edge_agg(
    const int* __restrict__ src, const int* __restrict__ dst,
    const float* __restrict__ a_s, const float* __restrict__ a_d,
    const float* __restrict__ m, const float* __restrict__ denom,
    const float* __restrict__ xw, float* __restrict__ outb) {
  int e = blockIdx.x;
  int s = src[e], d = dst[e];
  float alpha = expf(leaky(a_s[s] + a_d[d]) - m[d]) / (denom[d] + 1e-16f);
  int c = threadIdx.x;
  atomicAdd(&outb[(size_t)d * DD + c], alpha * xw[(size_t)s * DD + c]);
}

// in-place LayerNorm of (outb + conv_bias) with gamma/beta
__global__ __launch_bounds__(128) void k_ln(
    float* __restrict__ buf, const float* __restrict__ bias,
    const float* __restrict__ gamma, const float* __restrict__ beta) {
  __shared__ float s2[2];
  int n = blockIdx.x, c = threadIdx.x;
  float v = buf[(size_t)n * DD + c] + bias[c];
  float mu = blockReduceSum128(v, s2) * (1.f / DD);
  float diff = v - mu;
  float var = blockReduceSum128(diff * diff, s2) * (1.f / DD);
  buf[(size_t)n * DD + c] = diff * rsqrtf(var + 1e-5f) * gamma[c] + beta[c];
}

__global__ void k_zero(float4* __restrict__ p, int n4) {
  int i = blockIdx.x * blockDim.x + threadIdx.x;
  if (i < n4) p[i] = make_float4(0.f, 0.f, 0.f, 0.f);
}

// one block per edge: agg[d,:] += h[s,:]
__global__ __launch_bounds__(128) void k_edge_scatter(
    const int* __restrict__ src, const int* __restrict__ dst,
    const float* __restrict__ h, float* __restrict__ agg) {
  int e = blockIdx.x;
  int s = src[e], d = dst[e];
  int c = threadIdx.x;
  atomicAdd(&agg[(size_t)d * DD + c], h[(size_t)s * DD + c]);
}

// acc1 += agg @ w1t  (8 rows per block)
__global__ __launch_bounds__(128) void k_gemm_acc(
    const float* __restrict__ agg, const float* __restrict__ w1t,
    float* __restrict__ acc1) {
  __shared__ float sx[8][DD];
  int base = blockIdx.x * 8;
  int c = threadIdx.x;
  for (int r = 0; r < 8; ++r) sx[r][c] = agg[(size_t)(base + r) * DD + c];
  __syncthreads();
  float acc[8] = {0.f, 0.f, 0.f, 0.f, 0.f, 0.f, 0.f, 0.f};
  for (int k = 0; k < DD; ++k) {
    float w = w1t[k * DD + c];
    #pragma unroll
    for (int r = 0; r < 8; ++r) acc[r] = fmaf(sx[r][k], w, acc[r]);
  }
  #pragma unroll
  for (int r = 0; r < 8; ++r) acc1[(size_t)(base + r) * DD + c] += acc[r];
}

// fused classifier tail: relu(acc1) -> relu(@w2+b2) -> @w3+b3
__global__ __launch_bounds__(128) void k_tail(
    const float* __restrict__ acc1, const float* __restrict__ w2,
    const float* __restrict__ b2, const float* __restrict__ w3,
    const float* __restrict__ b3, float* __restrict__ out) {
  __shared__ float h1[DD];
  __shared__ float h2s[64];
  int n = blockIdx.x, tid = threadIdx.x;
  float v = acc1[(size_t)n * DD + tid];
  h1[tid] = v > 0.f ? v : 0.f;
  __syncthreads();
  if (tid < 64) {
    float acc = b2[tid];
    for (int k = 0; k < DD; ++k) acc = fmaf(h1[k], w2[k * 64 + tid], acc);
    h2s[tid] = acc > 0.f ? acc : 0.f;
  }
  __syncthreads();
  if (tid < 64) {
    float p = h2s[tid] * w3[tid];
    #pragma unroll
    for (int off = 32; off; off >>= 1) p += __shfl_down(p, off);
    if (tid == 0) out[n] = p + b3[0];
  }
}

// ---------- launch ----------

extern "C" void kernel_launch(void* const* d_in, const int* in_sizes, int n_in,
                              void* d_out, int out_size, void* d_ws, size_t ws_size,
                              hipStream_t stream) {
  const float* tx_x     = (const float*)d_in[0];
  const float* emb      = (const float*)d_in[1];
  const float* lin_w    = (const float*)d_in[2];
  const float* att_src  = (const float*)d_in[3];
  const float* att_dst  = (const float*)d_in[4];
  const float* conv_bias= (const float*)d_in[5];
  const float* ln_gamma = (const float*)d_in[6];
  const float* ln_beta  = (const float*)d_in[7];
  const float* w1       = (const float*)d_in[8];
  const float* b1       = (const float*)d_in[9];
  const float* w2       = (const float*)d_in[10];
  const float* b2       = (const float*)d_in[11];
  const float* w3       = (const float*)d_in[12];
  const float* b3       = (const float*)d_in[13];
  const int* entity_idx = (const int*)d_in[14];
  const int* edge_src   = (const int*)d_in[15];
  const int* edge_dst   = (const int*)d_in[16];
  float* out = (float*)d_out;

  float* ws = (float*)d_ws;
  float* acc1   = ws;                            // [NTX*DD]
  float* xw     = acc1 + (size_t)NTX * DD;       // [NE*DD]  (aliased as agg)
  float* outb   = xw + (size_t)NE * DD;          // [NE*DD]
  float* a_s    = outb + (size_t)NE * DD;        // [NE]
  float* a_d    = a_s + NE;                      // [NE]
  float* self_e = a_d + NE;                      // [NE]
  unsigned* m_mono = (unsigned*)(self_e + NE);   // [NE]
  float* m      = (float*)(m_mono + NE);         // [NE]
  float* denom  = m + NE;                        // [NE]
  float* las    = denom + NE;                    // [DD]
  float* lad    = las + DD;                      // [DD]
  float* agg    = xw;                            // alias: xw dead after k_edge_agg

  k_init_acc1<<<NTX / 8, DD, 0, stream>>>(tx_x, w1, b1, acc1);
  k_linw_att<<<1, DD, 0, stream>>>(lin_w, att_src, att_dst, las, lad);

  for (int t = 0; t < TT; ++t) {
    const float* emb_t = emb + (size_t)t * NE * DD;
    const int* idx_t   = entity_idx + (size_t)t * NE;
    const int* src     = edge_src + (size_t)t * EE;
    const int* dst     = edge_dst + (size_t)t * EE;
    const float* gamma = ln_gamma + t * DD;
    const float* beta  = ln_beta + t * DD;
    const float* w1t   = w1 + (size_t)(FF + t * DD) * DD;

    k_att<<<NE, DD, 0, stream>>>(emb_t, idx_t, las, lad, a_s, a_d, self_e, m_mono);
    k_gather_gemm<<<NE / 8, DD, 0, stream>>>(emb_t, idx_t, lin_w, xw);
    k_edge_max<<<(EE + 255) / 256, 256, 0, stream>>>(src, dst, a_s, a_d, m_mono);
    k_node_m<<<(NE + 255) / 256, 256, 0, stream>>>(m_mono, self_e, m, denom);
    k_edge_expsum<<<(EE + 255) / 256, 256, 0, stream>>>(src, dst, a_s, a_d, m, denom);
    k_self_out<<<(NE * DD + 255) / 256, 256, 0, stream>>>(xw, self_e, m, denom, outb);
    k_edge_agg<<<EE, DD, 0, stream>>>(src, dst, a_s, a_d, m, denom, xw, outb);
    k_ln<<<NE, DD, 0, stream>>>(outb, conv_bias, gamma, beta);
    k_zero<<<(NTX * DD / 4 + 255) / 256, 256, 0, stream>>>((float4*)agg, NTX * DD / 4);
    k_edge_scatter<<<EE, DD, 0, stream>>>(src, dst, outb, agg);
    k_gemm_acc<<<NTX / 8, DD, 0, stream>>>(agg, w1t, acc1);
  }

  k_tail<<<NTX, DD, 0, stream>>>(acc1, w2, b2, w3, b3, out);
}

// Round 2
// 4594.573 us; speedup vs baseline: 2.0068x; 2.0068x over previous
//
#include <hip/hip_runtime.h>

#define TT 11
#define NE 100000
#define NTX 100000
#define DD 128
#define EE 500000
#define FF 394

__device__ __forceinline__ float leaky(float x) { return x >= 0.f ? x : 0.2f * x; }

// ============================================================
// Tiled GEMM family: C[M x 128] = A[M x K] @ B[K x 128]
// block: 256 threads, 64 rows x 128 cols per block, k-chunk 32
// thread (ty=tid>>5, tx=tid&31) owns rows ty+8i (i<8), cols 4tx..4tx+3
// ============================================================

// acc1 = tx_x @ w1[0:FF] + b1
__global__ __launch_bounds__(256) void k_init_gemm(
    const float* __restrict__ A, const float* __restrict__ B,
    const float* __restrict__ bias, float* __restrict__ C) {
  __shared__ float As[64][32];
  __shared__ float Bs[32][128];
  int tid = threadIdx.x;
  int ty = tid >> 5, tx = tid & 31;
  int row0 = blockIdx.x * 64;
  float acc[8][4];
  #pragma unroll
  for (int i = 0; i < 8; ++i)
    #pragma unroll
    for (int j = 0; j < 4; ++j) acc[i][j] = 0.f;

  for (int k0 = 0; k0 < FF; k0 += 32) {
    int kc = FF - k0; if (kc > 32) kc = 32;
    for (int idx = tid; idx < 64 * 32; idx += 256) {
      int r = idx >> 5, kk = idx & 31;
      int rg = row0 + r;
      As[r][kk] = (kk < kc && rg < NTX) ? A[(size_t)rg * FF + k0 + kk] : 0.f;
    }
    for (int idx = tid; idx < 32 * 128; idx += 256) {
      int kk = idx >> 7, c = idx & 127;
      Bs[kk][c] = (kk < kc) ? B[(size_t)(k0 + kk) * DD + c] : 0.f;
    }
    __syncthreads();
    for (int kk = 0; kk < 32; ++kk) {
      float4 b = *(float4*)&Bs[kk][tx * 4];
      #pragma unroll
      for (int i = 0; i < 8; ++i) {
        float a = As[ty + 8 * i][kk];
        acc[i][0] = fmaf(a, b.x, acc[i][0]);
        acc[i][1] = fmaf(a, b.y, acc[i][1]);
        acc[i][2] = fmaf(a, b.z, acc[i][2]);
        acc[i][3] = fmaf(a, b.w, acc[i][3]);
      }
    }
    __syncthreads();
  }
  float4 bb = *(const float4*)&bias[tx * 4];
  #pragma unroll
  for (int i = 0; i < 8; ++i) {
    int rg = row0 + ty + 8 * i;
    if (rg < NTX) {
      float4 o = make_float4(acc[i][0] + bb.x, acc[i][1] + bb.y,
                             acc[i][2] + bb.z, acc[i][3] + bb.w);
      *(float4*)&C[(size_t)rg * DD + tx * 4] = o;
    }
  }
}

// xw = gather(emb_t, idx_t) @ lin_w ; also a_s = xw.att_src, a_d = xw.att_dst
__global__ __launch_bounds__(256) void k_xw_att(
    const float* __restrict__ emb_t, const int* __restrict__ idx_t,
    const float* __restrict__ B, const float* __restrict__ att_s,
    const float* __restrict__ att_d, float* __restrict__ C,
    float* __restrict__ a_s, float* __restrict__ a_d) {
  __shared__ float As[64][32];
  __shared__ float Bs[32][128];
  __shared__ int sidx[64];
  int tid = threadIdx.x;
  int ty = tid >> 5, tx = tid & 31;
  int row0 = blockIdx.x * 64;
  if (tid < 64) {
    int rg = row0 + tid;
    sidx[tid] = (rg < NE) ? idx_t[rg] : 0;
  }
  __syncthreads();
  float acc[8][4];
  #pragma unroll
  for (int i = 0; i < 8; ++i)
    #pragma unroll
    for (int j = 0; j < 4; ++j) acc[i][j] = 0.f;

  for (int k0 = 0; k0 < DD; k0 += 32) {
    for (int idx = tid; idx < 64 * 32; idx += 256) {
      int r = idx >> 5, kk = idx & 31;
      As[r][kk] = emb_t[(size_t)sidx[r] * DD + k0 + kk];
    }
    for (int idx = tid; idx < 32 * 128; idx += 256) {
      int kk = idx >> 7, c = idx & 127;
      Bs[kk][c] = B[(size_t)(k0 + kk) * DD + c];
    }
    __syncthreads();
    for (int kk = 0; kk < 32; ++kk) {
      float4 b = *(float4*)&Bs[kk][tx * 4];
      #pragma unroll
      for (int i = 0; i < 8; ++i) {
        float a = As[ty + 8 * i][kk];
        acc[i][0] = fmaf(a, b.x, acc[i][0]);
        acc[i][1] = fmaf(a, b.y, acc[i][1]);
        acc[i][2] = fmaf(a, b.z, acc[i][2]);
        acc[i][3] = fmaf(a, b.w, acc[i][3]);
      }
    }
    __syncthreads();
  }
  float4 sv = *(const float4*)&att_s[tx * 4];
  float4 dv = *(const float4*)&att_d[tx * 4];
  #pragma unroll
  for (int i = 0; i < 8; ++i) {
    int rg = row0 + ty + 8 * i;
    float ps = acc[i][0] * sv.x + acc[i][1] * sv.y + acc[i][2] * sv.z + acc[i][3] * sv.w;
    float pd = acc[i][0] * dv.x + acc[i][1] * dv.y + acc[i][2] * dv.z + acc[i][3] * dv.w;
    #pragma unroll
    for (int off = 16; off; off >>= 1) {
      ps += __shfl_xor(ps, off);
      pd += __shfl_xor(pd, off);
    }
    if (rg < NE) {
      *(float4*)&C[(size_t)rg * DD + tx * 4] =
          make_float4(acc[i][0], acc[i][1], acc[i][2], acc[i][3]);
      if (tx == 0) { a_s[rg] = ps; a_d[rg] = pd; }
    }
  }
}

// hw = h @ w1t  (K = 128, no bias)
__global__ __launch_bounds__(256) void k_hw_gemm(
    const float* __restrict__ A, const float* __restrict__ B, float* __restrict__ C) {
  __shared__ float As[64][32];
  __shared__ float Bs[32][128];
  int tid = threadIdx.x;
  int ty = tid >> 5, tx = tid & 31;
  int row0 = blockIdx.x * 64;
  float acc[8][4];
  #pragma unroll
  for (int i = 0; i < 8; ++i)
    #pragma unroll
    for (int j = 0; j < 4; ++j) acc[i][j] = 0.f;

  for (int k0 = 0; k0 < DD; k0 += 32) {
    for (int idx = tid; idx < 64 * 32; idx += 256) {
      int r = idx >> 5, kk = idx & 31;
      int rg = row0 + r;
      As[r][kk] = (rg < NE) ? A[(size_t)rg * DD + k0 + kk] : 0.f;
    }
    for (int idx = tid; idx < 32 * 128; idx += 256) {
      int kk = idx >> 7, c = idx & 127;
      Bs[kk][c] = B[(size_t)(k0 + kk) * DD + c];
    }
    __syncthreads();
    for (int kk = 0; kk < 32; ++kk) {
      float4 b = *(float4*)&Bs[kk][tx * 4];
      #pragma unroll
      for (int i = 0; i < 8; ++i) {
        float a = As[ty + 8 * i][kk];
        acc[i][0] = fmaf(a, b.x, acc[i][0]);
        acc[i][1] = fmaf(a, b.y, acc[i][1]);
        acc[i][2] = fmaf(a, b.z, acc[i][2]);
        acc[i][3] = fmaf(a, b.w, acc[i][3]);
      }
    }
    __syncthreads();
  }
  #pragma unroll
  for (int i = 0; i < 8; ++i) {
    int rg = row0 + ty + 8 * i;
    if (rg < NE)
      *(float4*)&C[(size_t)rg * DD + tx * 4] =
          make_float4(acc[i][0], acc[i][1], acc[i][2], acc[i][3]);
  }
}

// ============================================================
// CSR build (by dst), start[] destroyed into end[] by fill
// ============================================================
__global__ void k_hist(const int* __restrict__ dst, int* __restrict__ cnt) {
  int i = blockIdx.x * blockDim.x + threadIdx.x;
  if (i < EE) atomicAdd(&cnt[dst[i]], 1);
}

__global__ __launch_bounds__(256) void k_scan_a(const int* __restrict__ cnt,
                                                int* __restrict__ start,
                                                int* __restrict__ csum) {
  __shared__ int s[256];
  int i = blockIdx.x * 256 + threadIdx.x;
  int v = (i < NE) ? cnt[i] : 0;
  s[threadIdx.x] = v;
  __syncthreads();
  for (int off = 1; off < 256; off <<= 1) {
    int t = (threadIdx.x >= off) ? s[threadIdx.x - off] : 0;
    __syncthreads();
    s[threadIdx.x] += t;
    __syncthreads();
  }
  if (i < NE) start[i] = s[threadIdx.x] - v;  // exclusive
  if (threadIdx.x == 255) csum[blockIdx.x] = s[255];
}

__global__ __launch_bounds__(512) void k_scan_b(int* __restrict__ csum, int n) {
  __shared__ int s[512];
  int v = (threadIdx.x < n) ? csum[threadIdx.x] : 0;
  s[threadIdx.x] = v;
  __syncthreads();
  for (int off = 1; off < 512; off <<= 1) {
    int t = (threadIdx.x >= off) ? s[threadIdx.x - off] : 0;
    __syncthreads();
    s[threadIdx.x] += t;
    __syncthreads();
  }
  if (threadIdx.x < n) csum[threadIdx.x] = s[threadIdx.x] - v;  // exclusive
}

__global__ void k_scan_c(int* __restrict__ start, const int* __restrict__ csum) {
  int i = blockIdx.x * blockDim.x + threadIdx.x;
  if (i < NE) start[i] += csum[blockIdx.x * 256 / 256];  // csum[blockIdx.x]
}

// eidx[p] stores the SRC node of each edge, grouped by dst
__global__ void k_fill(const int* __restrict__ src, const int* __restrict__ dst,
                       int* __restrict__ start, int* __restrict__ eidx) {
  int i = blockIdx.x * blockDim.x + threadIdx.x;
  if (i >= EE) return;
  int p = atomicAdd(&start[dst[i]], 1);
  eidx[p] = src[i];
}

// ============================================================
// wave-per-dst fused attention: max / exp-sum / weighted gather / +bias / LN
// ============================================================
__global__ __launch_bounds__(256) void k_dst_attn(
    const int* __restrict__ start, const int* __restrict__ eidx,
    const float* __restrict__ a_s, const float* __restrict__ a_d,
    const float* __restrict__ xw, const float* __restrict__ cbias,
    const float* __restrict__ gamma, const float* __restrict__ beta,
    float* __restrict__ h) {
  int wid = (blockIdx.x * 256 + threadIdx.x) >> 6;
  int l = threadIdx.x & 63;
  if (wid >= NE) return;
  int d = wid;
  int end = start[d];
  int beg = (d == 0) ? 0 : start[d - 1];
  float ad = a_d[d];
  float eself = leaky(a_s[d] + ad);
  const float2* xw2 = (const float2*)xw;

  // pass 1: max over edges + self
  float mx = eself;
  for (int base = beg; base < end; base += 64) {
    int i = base + l;
    if (i < end) mx = fmaxf(mx, leaky(a_s[eidx[i]] + ad));
  }
  #pragma unroll
  for (int off = 32; off; off >>= 1) mx = fmaxf(mx, __shfl_xor(mx, off));

  // pass 2: unnormalized accumulate + denom
  float wself = expf(eself - mx);
  float denom = wself;
  float2 acc;
  float2 xs = xw2[(size_t)d * 64 + l];
  acc.x = wself * xs.x;
  acc.y = wself * xs.y;
  for (int base = beg; base < end; base += 64) {
    int len = end - base; if (len > 64) len = 64;
    int i = base + l;
    int sv = (i < end) ? eidx[i] : 0;
    float av = (i < end) ? a_s[sv] : 0.f;
    for (int j = 0; j < len; ++j) {
      int s = __shfl(sv, j);
      float a = __shfl(av, j);
      float w = expf(leaky(a + ad) - mx);
      denom += w;
      float2 v = xw2[(size_t)s * 64 + l];
      acc.x = fmaf(w, v.x, acc.x);
      acc.y = fmaf(w, v.y, acc.y);
    }
  }
  float inv = 1.f / (denom + 1e-16f);
  float2 cb = ((const float2*)cbias)[l];
  float v0 = acc.x * inv + cb.x;
  float v1 = acc.y * inv + cb.y;

  // LayerNorm over the 128-wide row (2 vals per lane)
  float s = v0 + v1;
  #pragma unroll
  for (int off = 32; off; off >>= 1) s += __shfl_xor(s, off);
  float mean = s * (1.f / 128.f);
  float d0 = v0 - mean, d1 = v1 - mean;
  float q = d0 * d0 + d1 * d1;
  #pragma unroll
  for (int off = 32; off; off >>= 1) q += __shfl_xor(q, off);
  float r = rsqrtf(q * (1.f / 128.f) + 1e-5f);
  float2 g = ((const float2*)gamma)[l];
  float2 b = ((const float2*)beta)[l];
  float2 o = make_float2(d0 * r * g.x + b.x, d1 * r * g.y + b.y);
  ((float2*)h)[(size_t)d * 64 + l] = o;
}

// wave-per-dst: acc1[d] += sum over edges of hw[src]
__global__ __launch_bounds__(256) void k_dst_sum_acc(
    const int* __restrict__ start, const int* __restrict__ eidx,
    const float* __restrict__ hw, float* __restrict__ acc1) {
  int wid = (blockIdx.x * 256 + threadIdx.x) >> 6;
  int l = threadIdx.x & 63;
  if (wid >= NE) return;
  int d = wid;
  int end = start[d];
  int beg = (d == 0) ? 0 : start[d - 1];
  if (beg == end) return;
  const float2* hw2 = (const float2*)hw;
  float2 acc = make_float2(0.f, 0.f);
  for (int base = beg; base < end; base += 64) {
    int len = end - base; if (len > 64) len = 64;
    int i = base + l;
    int sv = (i < end) ? eidx[i] : 0;
    for (int j = 0; j < len; ++j) {
      int s = __shfl(sv, j);
      float2 v = hw2[(size_t)s * 64 + l];
      acc.x += v.x;
      acc.y += v.y;
    }
  }
  float2* p = (float2*)acc1 + (size_t)d * 64 + l;
  float2 old = *p;
  *p = make_float2(old.x + acc.x, old.y + acc.y);
}

// fused classifier tail
__global__ __launch_bounds__(128) void k_tail(
    const float* __restrict__ acc1, const float* __restrict__ w2,
    const float* __restrict__ b2, const float* __restrict__ w3,
    const float* __restrict__ b3, float* __restrict__ out) {
  __shared__ float h1[DD];
  __shared__ float h2s[64];
  int n = blockIdx.x, tid = threadIdx.x;
  float v = acc1[(size_t)n * DD + tid];
  h1[tid] = v > 0.f ? v : 0.f;
  __syncthreads();
  if (tid < 64) {
    float acc = b2[tid];
    for (int k = 0; k < DD; ++k) acc = fmaf(h1[k], w2[k * 64 + tid], acc);
    h2s[tid] = acc > 0.f ? acc : 0.f;
  }
  __syncthreads();
  if (tid < 64) {
    float p = h2s[tid] * w3[tid];
    #pragma unroll
    for (int off = 32; off; off >>= 1) p += __shfl_down(p, off);
    if (tid == 0) out[n] = p + b3[0];
  }
}

// ---------- launch ----------

extern "C" void kernel_launch(void* const* d_in, const int* in_sizes, int n_in,
                              void* d_out, int out_size, void* d_ws, size_t ws_size,
                              hipStream_t stream) {
  const float* tx_x     = (const float*)d_in[0];
  const float* emb      = (const float*)d_in[1];
  const float* lin_w    = (const float*)d_in[2];
  const float* att_src  = (const float*)d_in[3];
  const float* att_dst  = (const float*)d_in[4];
  const float* conv_bias= (const float*)d_in[5];
  const float* ln_gamma = (const float*)d_in[6];
  const float* ln_beta  = (const float*)d_in[7];
  const float* w1       = (const float*)d_in[8];
  const float* b1       = (const float*)d_in[9];
  const float* w2       = (const float*)d_in[10];
  const float* b2       = (const float*)d_in[11];
  const float* w3       = (const float*)d_in[12];
  const float* b3       = (const float*)d_in[13];
  const int* entity_idx = (const int*)d_in[14];
  const int* edge_src   = (const int*)d_in[15];
  const int* edge_dst   = (const int*)d_in[16];
  float* out = (float*)d_out;

  float* ws   = (float*)d_ws;
  float* acc1 = ws;                         // 12.8M
  float* xw   = acc1 + (size_t)NTX * DD;    // 12.8M (aliased as hw)
  float* h    = xw + (size_t)NE * DD;       // 12.8M (cnt/csum alias during CSR build)
  float* a_s  = h + (size_t)NE * DD;        // 100K
  float* a_d  = a_s + NE;                   // 100K
  int* start  = (int*)(a_d + NE);           // 100K
  int* eidx   = start + NE;                 // 500K
  int* cnt    = (int*)h;                    // alias: h dead during CSR build
  int* csum   = cnt + 102400;               // alias, past cnt
  float* hw   = xw;                         // alias: xw dead after k_dst_attn

  const int NBLK = (NE + 255) / 256;        // 391
  const int GROWS = (NE + 63) / 64;         // 1563

  k_init_gemm<<<(NTX + 63) / 64, 256, 0, stream>>>(tx_x, w1, b1, acc1);

  for (int t = 0; t < TT; ++t) {
    const float* emb_t = emb + (size_t)t * NE * DD;
    const int* idx_t   = entity_idx + (size_t)t * NE;
    const int* src     = edge_src + (size_t)t * EE;
    const int* dst     = edge_dst + (size_t)t * EE;
    const float* gamma = ln_gamma + t * DD;
    const float* beta  = ln_beta + t * DD;
    const float* w1t   = w1 + (size_t)(FF + t * DD) * DD;

    k_xw_att<<<GROWS, 256, 0, stream>>>(emb_t, idx_t, lin_w, att_src, att_dst,
                                        xw, a_s, a_d);
    hipMemsetAsync(cnt, 0, NE * sizeof(int), stream);
    k_hist<<<(EE + 255) / 256, 256, 0, stream>>>(dst, cnt);
    k_scan_a<<<NBLK, 256, 0, stream>>>(cnt, start, csum);
    k_scan_b<<<1, 512, 0, stream>>>(csum, NBLK);
    k_scan_c<<<NBLK, 256, 0, stream>>>(start, csum);
    k_fill<<<(EE + 255) / 256, 256, 0, stream>>>(src, dst, start, eidx);
    k_dst_attn<<<(NE + 3) / 4, 256, 0, stream>>>(start, eidx, a_s, a_d, xw,
                                                 conv_bias, gamma, beta, h);
    k_hw_gemm<<<GROWS, 256, 0, stream>>>(h, w1t, hw);
    k_dst_sum_acc<<<(NE + 3) / 4, 256, 0, stream>>>(start, eidx, hw, acc1);
  }

  k_tail<<<NTX, DD, 0, stream>>>(acc1, w2, b2, w3, b3, out);
}